// Round 5
// baseline (474.071 us; speedup 1.0000x reference)
//
#include <hip/hip_runtime.h>
#include <math.h>

// ---------------------------------------------------------------------------
// Sizes
// ---------------------------------------------------------------------------
#define NB   512
#define TT   60
#define FF   5
#define HH   128
#define G4   512
#define NN   2500
#define KK   50

#define O0 800
#define O1 1500
#define O2 2100

// workspace layout (float offsets)
// fp16 weight arrays: 65536 halves = 32768 floats each.
// packed layout: halfidx = k2*1024 + jp*4 + jj*2 + kk   (j = 2*jp+jj, k = 2*k2+kk)
// -> uint2 index k2*256 + jp = {dword j0(kk0,kk1), dword j1(kk0,kk1)}
#define OFF_WA    0                    // W_hh0 fp16
#define OFF_WB    32768                // W_ih1 fp16
#define OFF_WC    65536                // W_hh1 fp16
#define OFF_W0T   98304                // [f][j] 5*512 fp32
#define OFF_B0    100864               // 512
#define OFF_B1    101376               // 512
#define OFF_A     101888               // 2500
#define OFF_FS    104388               // 512
#define OFF_NO    104900               // 512*2500
#define OFF_MEANS (OFF_NO + NB*NN)     // 2048
#define OFF_H1    (OFF_MEANS + 2048)   // 512*256

#define PREP_TOTAL 202692              // 3*65536 + 2560 + 512 + 512 + 2500

typedef _Float16 half2v __attribute__((ext_vector_type(2)));

#if defined(__has_builtin)
#if __has_builtin(__builtin_amdgcn_fdot2)
#define DOT2(a, b, c) __builtin_amdgcn_fdot2((a), (b), (c), false)
#endif
#endif
#ifndef DOT2
#define DOT2(a, b, c) fmaf((float)(a).x, (float)(b).x, fmaf((float)(a).y, (float)(b).y, (c)))
#endif

union WU { unsigned u; half2v h; };

__device__ __forceinline__ float sigf(float x) {
    return 1.0f / (1.0f + __expf(-x));
}
__device__ __forceinline__ float tanh_fast(float x) {
    float t = __expf(-2.0f * fabsf(x));
    float r = (1.0f - t) / (1.0f + t);
    return copysignf(r, x);
}

// 4 dot2: columns (j0,j1) x rows (r0,r1) for one k-pair
__device__ __forceinline__ void dot_pair(unsigned wj0, unsigned wj1,
                                         unsigned hr0, unsigned hr1,
                                         float& a00, float& a01,
                                         float& a10, float& a11)
{
    WU w0; w0.u = wj0;  WU w1; w1.u = wj1;
    WU h0; h0.u = hr0;  WU h1; h1.u = hr1;
    a00 = DOT2(w0.h, h0.h, a00);
    a01 = DOT2(w0.h, h1.h, a01);
    a10 = DOT2(w1.h, h0.h, a10);
    a11 = DOT2(w1.h, h1.h, a11);
}

// ---------------------------------------------------------------------------
// K0: prep — fp16 packed weight transposes, bias folds, a[n]
// ---------------------------------------------------------------------------
__global__ __launch_bounds__(256) void prep_kernel(
    const float* __restrict__ W_ih0, const float* __restrict__ W_hh0,
    const float* __restrict__ b_ih0, const float* __restrict__ b_hh0,
    const float* __restrict__ W_ih1, const float* __restrict__ W_hh1,
    const float* __restrict__ b_ih1, const float* __restrict__ b_hh1,
    const float* __restrict__ conn_w, const float* __restrict__ sens,
    float* __restrict__ ws)
{
    int i = blockIdx.x * 256 + threadIdx.x;
    if (i >= PREP_TOTAL) return;

    if (i < 196608) {                      // three fp16 weight arrays
        int m = i >> 16;                   // 0:Whh0 1:Wih1 2:Whh1
        int v = i & 65535;
        int k2 = v >> 10, rem = v & 1023;
        int jp = rem >> 2, jj = (rem >> 1) & 1, kk = rem & 1;
        int j = jp * 2 + jj;
        const float* src = (m == 0) ? W_hh0 : (m == 1) ? W_ih1 : W_hh1;
        _Float16* dst = (_Float16*)(ws + (m == 0 ? OFF_WA : m == 1 ? OFF_WB : OFF_WC));
        dst[v] = (_Float16)src[j * HH + (k2 * 2 + kk)];
    } else if (i < 199168) {               // W0T[f][j] = W_ih0[j][f]
        int v = i - 196608;
        int f = v >> 9, j = v & 511;
        ws[OFF_W0T + v] = W_ih0[j * FF + f];
    } else if (i < 199680) {
        int j = i - 199168;
        ws[OFF_B0 + j] = b_ih0[j] + b_hh0[j];
    } else if (i < 200192) {
        int j = i - 199680;
        ws[OFF_B1 + j] = b_ih1[j] + b_hh1[j];
    } else {
        int n = i - 200192;
        float s = 0.f;
        const float* cw = conn_w + n * KK;
        for (int k = 0; k < KK; ++k) s += cw[k];
        ws[OFF_A + n] = s * sens[n];
    }
}

// ---------------------------------------------------------------------------
// K1: fused 2-layer LSTM + feature head.
// 256 blocks x 1024 threads, 2 rows/block.
// tid -> jp = tid&255 (column pair 2jp,2jp+1), q = tid>>8 (k-quarter, 32 k's).
// Layer-1 weight slices (Wih1,Whh1: 16 uint2 each) live in VGPRs across the
// whole t-loop; only Whh0 streams from L2 (128KB/block-step).
// h fp16 in LDS, read as wave-uniform ds_read_b128 (2 k-pairs / read).
// x@W0T folded into the update phase (w0 in LDS).
// ---------------------------------------------------------------------------
__global__ __launch_bounds__(1024) void lstm_fused(
    const float* __restrict__ x,
    const float* __restrict__ ws_ro,
    const float* __restrict__ fp_w1, const float* __restrict__ fp_b1,
    const float* __restrict__ fp_w2, const float* __restrict__ fp_b2,
    float* __restrict__ feat_sum)
{
    __shared__ float xs[2][TT * FF + 4];
    __shared__ __align__(16) uint2 hb0h[HH / 2];   // [k2]{r0:half2, r1:half2}
    __shared__ __align__(16) uint2 hb1h[HH / 2];
    __shared__ float gp[4 * 256 * 4];              // [q][jp][jj][r]
    __shared__ float w0s[2560];                    // [f][j]
    __shared__ float t1s[2][64];
    __shared__ float bss[2][32];

    const int tid = threadIdx.x;
    const int jp = tid & 255;
    const int q = tid >> 8;
    const int brow = blockIdx.x * 2;

    for (int i = tid; i < 2 * TT * FF; i += 1024) {
        int r = i / (TT * FF), c = i % (TT * FF);
        xs[r][c] = x[(brow + r) * (TT * FF) + c];
    }
    for (int i = tid; i < 2560; i += 1024) w0s[i] = ws_ro[OFF_W0T + i];
    if (tid < HH / 2) { hb0h[tid] = make_uint2(0u, 0u); hb1h[tid] = make_uint2(0u, 0u); }

    const int ur = (tid >> 7) & 1, uk = tid & 127;
    float bi0 = 0.f, bf0 = 0.f, bg0 = 0.f, bo0 = 0.f;
    float bi1 = 0.f, bf1 = 0.f, bg1 = 0.f, bo1 = 0.f;
    if (tid < 256) {
        bi0 = ws_ro[OFF_B0 + uk];        bf0 = ws_ro[OFF_B0 + 128 + uk];
        bg0 = ws_ro[OFF_B0 + 256 + uk];  bo0 = ws_ro[OFF_B0 + 384 + uk];
        bi1 = ws_ro[OFF_B1 + uk];        bf1 = ws_ro[OFF_B1 + 128 + uk];
        bg1 = ws_ro[OFF_B1 + 256 + uk];  bo1 = ws_ro[OFF_B1 + 384 + uk];
    }
    float c0 = 0.f, c1 = 0.f;
    const int hwidx = (uk >> 1) * 4 + ur * 2 + (uk & 1);   // half index in hb*

    // ---- layer-1 weight slices -> registers (loop-invariant) ----
    const uint2* wBp = (const uint2*)(ws_ro + OFF_WB) + (q * 16) * 256 + jp;
    const uint2* wCp = (const uint2*)(ws_ro + OFF_WC) + (q * 16) * 256 + jp;
    uint2 wBr[16], wCr[16];
#pragma unroll
    for (int i = 0; i < 16; ++i) { wBr[i] = wBp[i * 256]; wCr[i] = wCp[i * 256]; }

    const uint2* wAq = (const uint2*)(ws_ro + OFF_WA) + (q * 16) * 256 + jp;
    const uint4* h0q = (const uint4*)hb0h + q * 8;
    const uint4* h1q = (const uint4*)hb1h + q * 8;
    float4* gpv4 = (float4*)gp;

    __syncthreads();

    for (int t = 0; t < TT; ++t) {
        // ---------- Phase A: layer-0 partial gates (Whh0 @ h0, streamed) ----
        float a00 = 0.f, a01 = 0.f, a10 = 0.f, a11 = 0.f;
#pragma unroll
        for (int i = 0; i < 8; ++i) {
            uint4 h4 = h0q[i];
            uint2 wv0 = wAq[(2 * i) * 256];
            uint2 wv1 = wAq[(2 * i + 1) * 256];
            dot_pair(wv0.x, wv0.y, h4.x, h4.y, a00, a01, a10, a11);
            dot_pair(wv1.x, wv1.y, h4.z, h4.w, a00, a01, a10, a11);
        }
        gpv4[q * 256 + jp] = make_float4(a00, a01, a10, a11);
        __syncthreads();

        // ---------- Phase B: layer-0 state update (+ x@W0T) ----------
        if (tid < 256) {
            float gi = bi0, gf = bf0, gg = bg0, go = bo0;
#pragma unroll
            for (int qq = 0; qq < 4; ++qq) {
                int base = qq * 1024 + (uk >> 1) * 4 + (uk & 1) * 2 + ur;
                gi += gp[base];
                gf += gp[base + 256];
                gg += gp[base + 512];
                go += gp[base + 768];
            }
            const float* xr = &xs[ur][t * FF];
#pragma unroll
            for (int f = 0; f < FF; ++f) {
                float xf = xr[f];
                gi = fmaf(w0s[f * G4 + uk],       xf, gi);
                gf = fmaf(w0s[f * G4 + 128 + uk], xf, gf);
                gg = fmaf(w0s[f * G4 + 256 + uk], xf, gg);
                go = fmaf(w0s[f * G4 + 384 + uk], xf, go);
            }
            c0 = sigf(gf) * c0 + sigf(gi) * tanh_fast(gg);
            ((_Float16*)hb0h)[hwidx] = (_Float16)(sigf(go) * tanh_fast(c0));
        }
        __syncthreads();

        // ---------- Phase C: layer-1 partial gates (regs: Wih1@h0 + Whh1@h1) --
        a00 = 0.f; a01 = 0.f; a10 = 0.f; a11 = 0.f;
#pragma unroll
        for (int i = 0; i < 8; ++i) {
            uint4 h04 = h0q[i];
            uint4 h14 = h1q[i];
            dot_pair(wBr[2 * i].x,     wBr[2 * i].y,     h04.x, h04.y, a00, a01, a10, a11);
            dot_pair(wBr[2 * i + 1].x, wBr[2 * i + 1].y, h04.z, h04.w, a00, a01, a10, a11);
            dot_pair(wCr[2 * i].x,     wCr[2 * i].y,     h14.x, h14.y, a00, a01, a10, a11);
            dot_pair(wCr[2 * i + 1].x, wCr[2 * i + 1].y, h14.z, h14.w, a00, a01, a10, a11);
        }
        gpv4[q * 256 + jp] = make_float4(a00, a01, a10, a11);
        __syncthreads();

        // ---------- Phase D: layer-1 state update ----------
        if (tid < 256) {
            float gi = bi1, gf = bf1, gg = bg1, go = bo1;
#pragma unroll
            for (int qq = 0; qq < 4; ++qq) {
                int base = qq * 1024 + (uk >> 1) * 4 + (uk & 1) * 2 + ur;
                gi += gp[base];
                gf += gp[base + 256];
                gg += gp[base + 512];
                go += gp[base + 768];
            }
            c1 = sigf(gf) * c1 + sigf(gi) * tanh_fast(gg);
            ((_Float16*)hb1h)[hwidx] = (_Float16)(sigf(go) * tanh_fast(c1));
        }
        __syncthreads();
    }

    // ---------- head MLP ----------
    if (tid < 128) {
        int r = tid >> 6, m = tid & 63;
        float acc = fp_b1[m];
        const float* wp = fp_w1 + m * HH;
        const _Float16* h1h = (const _Float16*)hb1h;
        for (int k = 0; k < HH; ++k)
            acc = fmaf(wp[k], (float)h1h[(k >> 1) * 4 + r * 2 + (k & 1)], acc);
        t1s[r][m] = fmaxf(acc, 0.f);
    }
    __syncthreads();
    if (tid < 64) {
        int r = tid >> 5, qq = tid & 31;
        float acc = fp_b2[qq];
        const float* wp = fp_w2 + qq * 64;
        for (int m = 0; m < 64; ++m) acc = fmaf(wp[m], t1s[r][m], acc);
        bss[r][qq] = tanh_fast(acc);
    }
    __syncthreads();
    if (tid < 2) {
        float s = 0.f;
        for (int qq = 0; qq < 32; ++qq) s += bss[tid][qq];
        feat_sum[brow + tid] = s;
    }
}

// ---------------------------------------------------------------------------
// K2: neuron activations + group means.  one block per batch row.
// ---------------------------------------------------------------------------
__global__ __launch_bounds__(256) void neuron_kernel(
    const float* __restrict__ feat_sum, const float* __restrict__ a,
    const float* __restrict__ thr,
    float* __restrict__ no, float* __restrict__ means)
{
    const int b = blockIdx.x;
    const float s = feat_sum[b];
    float g0 = 0.f, g1 = 0.f, g2 = 0.f, g3 = 0.f;
    for (int n = threadIdx.x; n < NN; n += 256) {
        float pre = s * a[n];
        float v;
        if (n < O0)        { v = sigf(pre - thr[n]);          g0 += v; }
        else if (n < O1)   { v = tanh_fast(pre);              g1 += v; }
        else if (n < O2)   { v = fmaxf(pre - thr[n], 0.f);    g2 += v; }
        else               { v = sigf(pre);                   g3 += v; }
        no[b * NN + n] = v;
    }
    __shared__ float red[4][256];
    red[0][threadIdx.x] = g0; red[1][threadIdx.x] = g1;
    red[2][threadIdx.x] = g2; red[3][threadIdx.x] = g3;
    __syncthreads();
    if (threadIdx.x < 4) {
        float acc = 0.f;
        for (int i = 0; i < 256; ++i) acc += red[threadIdx.x][i];
        const float inv[4] = {1.f / 800.f, 1.f / 700.f, 1.f / 600.f, 1.f / 400.f};
        means[b * 4 + threadIdx.x] = acc * inv[threadIdx.x];
    }
}

// ---------------------------------------------------------------------------
// K3: h1 = relu(no @ int_w1.T + int_b1)  M=512 N=256 K=2500
// ---------------------------------------------------------------------------
__global__ __launch_bounds__(256) void gemm_h1(
    const float* __restrict__ no,
    const float* __restrict__ int_w1,   // 256 x 2500
    const float* __restrict__ int_b1,
    float* __restrict__ h1)
{
    __shared__ float As[32][33];
    __shared__ float Bs[32][33];
    const int b0 = blockIdx.x * 32;
    const int m0 = blockIdx.y * 32;
    const int tid = threadIdx.x;
    const int ty = tid >> 4, tx = tid & 15;
    const int li = tid >> 3;
    const int lj = (tid & 7) * 4;

    float acc00 = 0.f, acc01 = 0.f, acc10 = 0.f, acc11 = 0.f;

    for (int k0 = 0; k0 < NN; k0 += 32) {
        float4 av = make_float4(0.f, 0.f, 0.f, 0.f);
        if (k0 + lj < NN)
            av = *(const float4*)(no + (b0 + li) * NN + k0 + lj);
        As[li][lj + 0] = av.x; As[li][lj + 1] = av.y;
        As[li][lj + 2] = av.z; As[li][lj + 3] = av.w;

        float4 wv = make_float4(0.f, 0.f, 0.f, 0.f);
        if (k0 + lj < NN)
            wv = *(const float4*)(int_w1 + (m0 + li) * NN + k0 + lj);
        Bs[lj + 0][li] = wv.x; Bs[lj + 1][li] = wv.y;
        Bs[lj + 2][li] = wv.z; Bs[lj + 3][li] = wv.w;
        __syncthreads();

#pragma unroll 8
        for (int kk = 0; kk < 32; ++kk) {
            float a0 = As[ty * 2][kk],  a1 = As[ty * 2 + 1][kk];
            float w0 = Bs[kk][tx * 2],  w1 = Bs[kk][tx * 2 + 1];
            acc00 += a0 * w0; acc01 += a0 * w1;
            acc10 += a1 * w0; acc11 += a1 * w1;
        }
        __syncthreads();
    }
    const int bi = b0 + ty * 2, mj = m0 + tx * 2;
    h1[bi * 256 + mj]           = fmaxf(acc00 + int_b1[mj], 0.f);
    h1[bi * 256 + mj + 1]       = fmaxf(acc01 + int_b1[mj + 1], 0.f);
    h1[(bi + 1) * 256 + mj]     = fmaxf(acc10 + int_b1[mj], 0.f);
    h1[(bi + 1) * 256 + mj + 1] = fmaxf(acc11 + int_b1[mj + 1], 0.f);
}

// ---------------------------------------------------------------------------
// K4: tail MLP + output assembly.  one wave per batch row.
// ---------------------------------------------------------------------------
__global__ __launch_bounds__(64) void tail_kernel(
    const float* __restrict__ h1,
    const float* __restrict__ int_w2, const float* __restrict__ int_b2,
    const float* __restrict__ int_w3, const float* __restrict__ int_b3,
    const float* __restrict__ tw, const float* __restrict__ tb,
    const float* __restrict__ pw, const float* __restrict__ pb,
    const float* __restrict__ kw, const float* __restrict__ kb,
    const float* __restrict__ vw, const float* __restrict__ vb,
    const float* __restrict__ cw, const float* __restrict__ cb,
    const float* __restrict__ means,
    float* __restrict__ out)
{
    const int b = blockIdx.x;
    const int lane = threadIdx.x;
    __shared__ float h2s[64];
    __shared__ float ints[32];
    __shared__ float outs[16];

    {
        float acc = int_b2[lane];
        const float* hp = h1 + b * 256;
        const float* wp = int_w2 + lane * 256;
        for (int m = 0; m < 256; ++m) acc += wp[m] * hp[m];
        h2s[lane] = fmaxf(acc, 0.f);
    }
    __syncthreads();
    if (lane < 32) {
        float acc = int_b3[lane];
        const float* wp = int_w3 + lane * 64;
        for (int m = 0; m < 64; ++m) acc += wp[m] * h2s[m];
        ints[lane] = tanh_fast(acc);
    }
    __syncthreads();
    if (lane < 15) {
        const float* wsel; float bsel;
        if (lane < 3)       { wsel = tw + lane * 32;       bsel = tb[lane]; }
        else if (lane < 9)  { wsel = pw + (lane - 3) * 32; bsel = pb[lane - 3]; }
        else if (lane < 13) { wsel = kw + (lane - 9) * 32; bsel = kb[lane - 9]; }
        else if (lane == 13){ wsel = vw;                   bsel = vb[0]; }
        else                { wsel = cw;                   bsel = cb[0]; }
        float acc = bsel;
        for (int qq = 0; qq < 32; ++qq) acc += wsel[qq] * ints[qq];
        outs[lane] = acc;
    }
    __syncthreads();
    if (lane < 20) {
        float v;
        if (lane < 15)       v = outs[lane];
        else if (lane == 15) v = sigf(outs[14]);
        else                 v = means[b * 4 + (lane - 16)];
        out[b * 20 + lane] = v;
    }
}

// ---------------------------------------------------------------------------
extern "C" void kernel_launch(void* const* d_in, const int* in_sizes, int n_in,
                              void* d_out, int out_size, void* d_ws, size_t ws_size,
                              hipStream_t stream)
{
    const float* x      = (const float*)d_in[0];
    const float* W_ih0  = (const float*)d_in[1];
    const float* W_hh0  = (const float*)d_in[2];
    const float* b_ih0  = (const float*)d_in[3];
    const float* b_hh0  = (const float*)d_in[4];
    const float* W_ih1  = (const float*)d_in[5];
    const float* W_hh1  = (const float*)d_in[6];
    const float* b_ih1  = (const float*)d_in[7];
    const float* b_hh1  = (const float*)d_in[8];
    const float* fp_w1  = (const float*)d_in[9];
    const float* fp_b1  = (const float*)d_in[10];
    const float* fp_w2  = (const float*)d_in[11];
    const float* fp_b2  = (const float*)d_in[12];
    const float* conn_w = (const float*)d_in[13];
    const float* sens   = (const float*)d_in[14];
    const float* thr    = (const float*)d_in[15];
    const float* int_w1 = (const float*)d_in[16];
    const float* int_b1 = (const float*)d_in[17];
    const float* int_w2 = (const float*)d_in[18];
    const float* int_b2 = (const float*)d_in[19];
    const float* int_w3 = (const float*)d_in[20];
    const float* int_b3 = (const float*)d_in[21];
    const float* tw     = (const float*)d_in[22];
    const float* tb     = (const float*)d_in[23];
    const float* pw     = (const float*)d_in[24];
    const float* pb     = (const float*)d_in[25];
    const float* kw     = (const float*)d_in[26];
    const float* kb     = (const float*)d_in[27];
    const float* vw     = (const float*)d_in[28];
    const float* vb     = (const float*)d_in[29];
    const float* cw     = (const float*)d_in[30];
    const float* cb     = (const float*)d_in[31];
    // d_in[32] = conn_idx -- unused: acts is a feat_sum broadcast, so the
    // gather/einsum collapses to feat_sum[b] * rowsum(conn_w)[n].

    float* ws = (float*)d_ws;
    float* out = (float*)d_out;

    prep_kernel<<<(PREP_TOTAL + 255) / 256, 256, 0, stream>>>(
        W_ih0, W_hh0, b_ih0, b_hh0, W_ih1, W_hh1, b_ih1, b_hh1,
        conn_w, sens, ws);

    lstm_fused<<<NB / 2, 1024, 0, stream>>>(
        x, ws, fp_w1, fp_b1, fp_w2, fp_b2, ws + OFF_FS);

    neuron_kernel<<<NB, 256, 0, stream>>>(
        ws + OFF_FS, ws + OFF_A, thr, ws + OFF_NO, ws + OFF_MEANS);

    {
        dim3 grid(NB / 32, 256 / 32);
        gemm_h1<<<grid, 256, 0, stream>>>(
            ws + OFF_NO, int_w1, int_b1, ws + OFF_H1);
    }

    tail_kernel<<<NB, 64, 0, stream>>>(
        ws + OFF_H1, int_w2, int_b2, int_w3, int_b3,
        tw, tb, pw, pb, kw, kb, vw, vb, cw, cb,
        ws + OFF_MEANS, out);
}

// Round 6
// 392.379 us; speedup vs baseline: 1.2082x; 1.2082x over previous
//
#include <hip/hip_runtime.h>
#include <math.h>

// ---------------------------------------------------------------------------
// Sizes
// ---------------------------------------------------------------------------
#define NB   512
#define TT   60
#define FF   5
#define HH   128
#define G4   512
#define NN   2500
#define KK   50

#define O0 800
#define O1 1500
#define O2 2100

// ---------------------------------------------------------------------------
// Workspace layout (float offsets).
// B-fragment streams are pre-swizzled into MFMA B-operand order:
//   B-frag element: k = kb*32 + (l>>4)*8 + j ; n = g*128 + w*16 + (l&15)
//   frag = 64 lanes x 8 halves = 1KB, loaded as one dwordx4 per lane.
// Gate columns are grouped per wave as [i|f|g|o] of the wave's 16 u's, so the
// 4 gates of one hidden unit land in the SAME lane across the 4 g-frags.
// ---------------------------------------------------------------------------
#define OFF_B0F   0                        // L0 B-frags: 8w*5kb*4g*512h = 81920 halves
#define OFF_B1F   40960                    // L1 B-frags: 8w*8kb*4g*512h = 131072 halves
#define OFF_XA    106496                   // x A-frags: 32b*60t*512h = 983040 halves
#define OFF_BIAS0 598016                   // 512
#define OFF_BIAS1 598528                   // 512
#define OFF_A     599040                   // 2500
#define OFF_FS    601540                   // 512
#define OFF_MEANS 602052                   // 2048
#define OFF_H1    604100                   // 512*256

#define PREP_T0 81920                      // end L0B (halves)
#define PREP_T1 212992                     // end L1B
#define PREP_T2 1196032                    // end xA
#define PREP_T3 1196544                    // end bias0
#define PREP_T4 1197056                    // end bias1
#define PREP_TOTAL 1199556                 // end a[n]

typedef _Float16 f16x8 __attribute__((ext_vector_type(8)));
typedef float f32x4 __attribute__((ext_vector_type(4)));

__device__ __forceinline__ float sigf(float x) {
    return 1.0f / (1.0f + __expf(-x));
}
// tanh via 2*sigmoid(2x)-1 : 5 VALU ops, correct limits at +-inf
__device__ __forceinline__ float tanh2(float x) {
    float e = __expf(-2.0f * x);
    return fmaf(2.0f, 1.0f / (1.0f + e), -1.0f);
}

// ---------------------------------------------------------------------------
// K0: prep — B-frag swizzled fp16 weights, x A-frags, bias folds, a[n]
// ---------------------------------------------------------------------------
__global__ __launch_bounds__(256) void prep_kernel(
    const float* __restrict__ x,
    const float* __restrict__ W_ih0, const float* __restrict__ W_hh0,
    const float* __restrict__ b_ih0, const float* __restrict__ b_hh0,
    const float* __restrict__ W_ih1, const float* __restrict__ W_hh1,
    const float* __restrict__ b_ih1, const float* __restrict__ b_hh1,
    const float* __restrict__ conn_w, const float* __restrict__ sens,
    float* __restrict__ ws)
{
    int i = blockIdx.x * 256 + threadIdx.x;
    if (i >= PREP_TOTAL) return;

    if (i < PREP_T0) {                       // layer-0 B frags (K=160 padded)
        int j = i & 7, l = (i >> 3) & 63;
        int rest = i >> 9;                   // (w*5+kb)*4+g
        int g = rest & 3;
        int kbw = rest >> 2;
        int kb = kbw % 5, w = kbw / 5;
        int k = kb * 32 + (l >> 4) * 8 + j;
        int n = g * 128 + w * 16 + (l & 15);
        float val = 0.f;
        if (k < 128)       val = W_hh0[n * HH + k];
        else if (k < 133)  val = W_ih0[n * FF + (k - 128)];
        ((_Float16*)(ws + OFF_B0F))[i] = (_Float16)val;
    } else if (i < PREP_T1) {                // layer-1 B frags (K=256: Wih1|Whh1)
        int v = i - PREP_T0;
        int j = v & 7, l = (v >> 3) & 63;
        int rest = v >> 9;                   // (w*8+kb)*4+g
        int g = rest & 3;
        int kb = (rest >> 2) & 7;
        int w = rest >> 5;
        int k = kb * 32 + (l >> 4) * 8 + j;
        int n = g * 128 + w * 16 + (l & 15);
        float val = (k < 128) ? W_ih1[n * HH + k] : W_hh1[n * HH + (k - 128)];
        ((_Float16*)(ws + OFF_B1F))[v] = (_Float16)val;
    } else if (i < PREP_T2) {                // x A-frags (kb=4 of layer-0 A)
        int v = i - PREP_T1;
        int j = v & 7, l = (v >> 3) & 63;
        int rest = v >> 9;                   // b*60+t
        int t = rest % 60, bb = rest / 60;
        float val = 0.f;
        if (l < 16 && j < 5)                 // k=128+j < 133
            val = x[(bb * 16 + (l & 15)) * (TT * FF) + t * FF + j];
        ((_Float16*)(ws + OFF_XA))[v] = (_Float16)val;
    } else if (i < PREP_T3) {
        int j = i - PREP_T2;
        ws[OFF_BIAS0 + j] = b_ih0[j] + b_hh0[j];
    } else if (i < PREP_T4) {
        int j = i - PREP_T3;
        ws[OFF_BIAS1 + j] = b_ih1[j] + b_hh1[j];
    } else {
        int n = i - PREP_T4;
        float s = 0.f;
        const float* cw = conn_w + n * KK;
        for (int k = 0; k < KK; ++k) s += cw[k];
        ws[OFF_A + n] = s * sens[n];
    }
}

// ---------------------------------------------------------------------------
// K1: MFMA 2-layer LSTM + feature head.
// 32 blocks x 512 threads (8 waves); block owns 16 batch rows.
// Wave w owns u in [w*16,(w+1)*16): computes gate-frags [i|f|g|o] for its u's.
// Lane-local cell update: lane l holds gates for u=w*16+(l&15),
// rows (l>>4)*4+reg (MFMA C layout col=lane&15, row=(lane>>4)*4+reg).
// h kept in LDS in exact A-frag order: hcat[kb][lane][8] halves;
// kb0-3 = h0 (k=u), kb4-7 = h1 (k=u+128). Layer-0 A kb4 = x (global stream).
// ---------------------------------------------------------------------------
__global__ __launch_bounds__(512) void lstm_mfma(
    const float* __restrict__ ws_ro,
    const float* __restrict__ fp_w1, const float* __restrict__ fp_b1,
    const float* __restrict__ fp_w2, const float* __restrict__ fp_b2,
    float* __restrict__ feat_sum)
{
    __shared__ __align__(16) _Float16 hcat[8 * 512];   // 8KB
    __shared__ float t1s[16][65];
    __shared__ float bss[16][33];

    const int tid = threadIdx.x;
    const int w = tid >> 6, l = tid & 63;
    const int u = w * 16 + (l & 15);
    const int row0 = (l >> 4) * 4;
    const int bb = blockIdx.x;

    // zero h state
    ((uint4*)hcat)[tid] = make_uint4(0u, 0u, 0u, 0u);

    float bia0[4], bia1[4];
#pragma unroll
    for (int g = 0; g < 4; ++g) {
        bia0[g] = ws_ro[OFF_BIAS0 + g * 128 + u];
        bia1[g] = ws_ro[OFF_BIAS1 + g * 128 + u];
    }
    float c0[4] = {0.f, 0.f, 0.f, 0.f};
    float c1[4] = {0.f, 0.f, 0.f, 0.f};

    const f16x8* B0 = (const f16x8*)(ws_ro + OFF_B0F) + w * 20 * 64 + l;
    const f16x8* B1 = (const f16x8*)(ws_ro + OFF_B1F) + w * 32 * 64 + l;
    const f16x8* XA = (const f16x8*)(ws_ro + OFF_XA) + bb * 60 * 64 + l;
    const f16x8* HF = (const f16x8*)hcat;

    // h write base (halves): element (row,k): (k>>5)*512 + (row+((k>>3)&3)*16)*8 + (k&7)
    const int h0base = (u >> 5) * 512 + ((u >> 3) & 3) * 128 + (u & 7);
    const int h1base = h0base + 2048;          // k = u+128

    __syncthreads();

    for (int t = 0; t < TT; ++t) {
        // ---------- layer 0: gates = [h0|x] @ B0  (K=160) ----------
        f32x4 a0 = {0.f,0.f,0.f,0.f}, a1 = {0.f,0.f,0.f,0.f};
        f32x4 a2 = {0.f,0.f,0.f,0.f}, a3 = {0.f,0.f,0.f,0.f};
        f16x8 xaf = XA[t * 64];
#pragma unroll
        for (int kb = 0; kb < 4; ++kb) {
            f16x8 af = HF[kb * 64 + l];
            a0 = __builtin_amdgcn_mfma_f32_16x16x32_f16(af, B0[(kb*4+0)*64], a0, 0,0,0);
            a1 = __builtin_amdgcn_mfma_f32_16x16x32_f16(af, B0[(kb*4+1)*64], a1, 0,0,0);
            a2 = __builtin_amdgcn_mfma_f32_16x16x32_f16(af, B0[(kb*4+2)*64], a2, 0,0,0);
            a3 = __builtin_amdgcn_mfma_f32_16x16x32_f16(af, B0[(kb*4+3)*64], a3, 0,0,0);
        }
        a0 = __builtin_amdgcn_mfma_f32_16x16x32_f16(xaf, B0[(16+0)*64], a0, 0,0,0);
        a1 = __builtin_amdgcn_mfma_f32_16x16x32_f16(xaf, B0[(16+1)*64], a1, 0,0,0);
        a2 = __builtin_amdgcn_mfma_f32_16x16x32_f16(xaf, B0[(16+2)*64], a2, 0,0,0);
        a3 = __builtin_amdgcn_mfma_f32_16x16x32_f16(xaf, B0[(16+3)*64], a3, 0,0,0);

        float h0v[4];
#pragma unroll
        for (int r = 0; r < 4; ++r) {
            float gi = sigf(a0[r] + bia0[0]);
            float gf = sigf(a1[r] + bia0[1]);
            float gg = tanh2(a2[r] + bia0[2]);
            float go = sigf(a3[r] + bia0[3]);
            c0[r] = gf * c0[r] + gi * gg;
            h0v[r] = go * tanh2(c0[r]);
        }
        __syncthreads();                        // all reads of old h0 done
#pragma unroll
        for (int r = 0; r < 4; ++r)
            hcat[h0base + (row0 + r) * 8] = (_Float16)h0v[r];
        __syncthreads();                        // new h0 visible

        // ---------- layer 1: gates = [h0|h1] @ B1  (K=256) ----------
        f32x4 b0a = {0.f,0.f,0.f,0.f}, b1a = {0.f,0.f,0.f,0.f};
        f32x4 b2a = {0.f,0.f,0.f,0.f}, b3a = {0.f,0.f,0.f,0.f};
#pragma unroll
        for (int kb = 0; kb < 8; ++kb) {
            f16x8 af = HF[kb * 64 + l];
            b0a = __builtin_amdgcn_mfma_f32_16x16x32_f16(af, B1[(kb*4+0)*64], b0a, 0,0,0);
            b1a = __builtin_amdgcn_mfma_f32_16x16x32_f16(af, B1[(kb*4+1)*64], b1a, 0,0,0);
            b2a = __builtin_amdgcn_mfma_f32_16x16x32_f16(af, B1[(kb*4+2)*64], b2a, 0,0,0);
            b3a = __builtin_amdgcn_mfma_f32_16x16x32_f16(af, B1[(kb*4+3)*64], b3a, 0,0,0);
        }
        float h1v[4];
#pragma unroll
        for (int r = 0; r < 4; ++r) {
            float gi = sigf(b0a[r] + bia1[0]);
            float gf = sigf(b1a[r] + bia1[1]);
            float gg = tanh2(b2a[r] + bia1[2]);
            float go = sigf(b3a[r] + bia1[3]);
            c1[r] = gf * c1[r] + gi * gg;
            h1v[r] = go * tanh2(c1[r]);
        }
        __syncthreads();                        // all reads of old h1 done
#pragma unroll
        for (int r = 0; r < 4; ++r)
            hcat[h1base + (row0 + r) * 8] = (_Float16)h1v[r];
        __syncthreads();                        // new h1 visible
    }

    // ---------- head MLP on hlast = h1 (hcat kb4-7) ----------
    for (int idx = tid; idx < 16 * 64; idx += 512) {
        int r = idx >> 6, m = idx & 63;
        float acc = fp_b1[m];
        const float* wp = fp_w1 + m * HH;
        for (int k = 0; k < HH; ++k) {
            float hv = (float)hcat[(4 + (k >> 5)) * 512 +
                                   (r + ((k >> 3) & 3) * 16) * 8 + (k & 7)];
            acc = fmaf(wp[k], hv, acc);
        }
        t1s[r][m] = fmaxf(acc, 0.f);
    }
    __syncthreads();
    if (tid < 16 * 32) {
        int r = tid >> 5, q = tid & 31;
        float acc = fp_b2[q];
        const float* wp = fp_w2 + q * 64;
        for (int m = 0; m < 64; ++m) acc = fmaf(wp[m], t1s[r][m], acc);
        bss[r][q] = tanh2(acc);
    }
    __syncthreads();
    if (tid < 16) {
        float s = 0.f;
        for (int q = 0; q < 32; ++q) s += bss[tid][q];
        feat_sum[bb * 16 + tid] = s;
    }
}

// ---------------------------------------------------------------------------
// shared neuron activation
// ---------------------------------------------------------------------------
__device__ __forceinline__ float actn(int n, float pre, float th) {
    if (n < O0)       return sigf(pre - th);
    else if (n < O1)  return tanh2(pre);
    else if (n < O2)  return fmaxf(pre - th, 0.f);
    else              return sigf(pre);
}

// ---------------------------------------------------------------------------
// K2: group means only (neuron activations recomputed in K3 — no `no` array)
// ---------------------------------------------------------------------------
__global__ __launch_bounds__(256) void means_kernel(
    const float* __restrict__ feat_sum, const float* __restrict__ a,
    const float* __restrict__ thr, float* __restrict__ means)
{
    const int b = blockIdx.x;
    const float s = feat_sum[b];
    float g0 = 0.f, g1 = 0.f, g2 = 0.f, g3 = 0.f;
    for (int n = threadIdx.x; n < NN; n += 256) {
        float v = actn(n, s * a[n], thr[n]);
        if (n < O0) g0 += v; else if (n < O1) g1 += v;
        else if (n < O2) g2 += v; else g3 += v;
    }
    __shared__ float red[4][256];
    red[0][threadIdx.x] = g0; red[1][threadIdx.x] = g1;
    red[2][threadIdx.x] = g2; red[3][threadIdx.x] = g3;
    __syncthreads();
    if (threadIdx.x < 4) {
        float acc = 0.f;
        for (int i = 0; i < 256; ++i) acc += red[threadIdx.x][i];
        const float inv[4] = {1.f/800.f, 1.f/700.f, 1.f/600.f, 1.f/400.f};
        means[b * 4 + threadIdx.x] = acc * inv[threadIdx.x];
    }
}

// ---------------------------------------------------------------------------
// K3: h1 = relu(no @ int_w1.T + int_b1), no recomputed on the fly.
// M=512 N=256 K=2500, 32x32 tiles.
// ---------------------------------------------------------------------------
__global__ __launch_bounds__(256) void gemm_h1(
    const float* __restrict__ feat_sum,
    const float* __restrict__ aw, const float* __restrict__ thr,
    const float* __restrict__ int_w1,   // 256 x 2500
    const float* __restrict__ int_b1,
    float* __restrict__ h1)
{
    __shared__ float As[32][33];
    __shared__ float Bs[32][33];
    const int b0 = blockIdx.x * 32;
    const int m0 = blockIdx.y * 32;
    const int tid = threadIdx.x;
    const int ty = tid >> 4, tx = tid & 15;
    const int li = tid >> 3;
    const int lj = (tid & 7) * 4;

    const float s_li = feat_sum[b0 + li];

    float acc00 = 0.f, acc01 = 0.f, acc10 = 0.f, acc11 = 0.f;

    for (int k0 = 0; k0 < NN; k0 += 32) {
        float4 av = make_float4(0.f, 0.f, 0.f, 0.f);
        if (k0 + lj < NN) {
            float4 aa = *(const float4*)(aw + k0 + lj);
            float4 tt = *(const float4*)(thr + k0 + lj);
            int n = k0 + lj;
            av.x = actn(n + 0, s_li * aa.x, tt.x);
            av.y = actn(n + 1, s_li * aa.y, tt.y);
            av.z = actn(n + 2, s_li * aa.z, tt.z);
            av.w = actn(n + 3, s_li * aa.w, tt.w);
        }
        As[li][lj + 0] = av.x; As[li][lj + 1] = av.y;
        As[li][lj + 2] = av.z; As[li][lj + 3] = av.w;

        float4 wv = make_float4(0.f, 0.f, 0.f, 0.f);
        if (k0 + lj < NN)
            wv = *(const float4*)(int_w1 + (m0 + li) * NN + k0 + lj);
        Bs[lj + 0][li] = wv.x; Bs[lj + 1][li] = wv.y;
        Bs[lj + 2][li] = wv.z; Bs[lj + 3][li] = wv.w;
        __syncthreads();

#pragma unroll 8
        for (int kk = 0; kk < 32; ++kk) {
            float a0 = As[ty * 2][kk],  a1 = As[ty * 2 + 1][kk];
            float w0 = Bs[kk][tx * 2],  w1 = Bs[kk][tx * 2 + 1];
            acc00 += a0 * w0; acc01 += a0 * w1;
            acc10 += a1 * w0; acc11 += a1 * w1;
        }
        __syncthreads();
    }
    const int bi = b0 + ty * 2, mj = m0 + tx * 2;
    h1[bi * 256 + mj]           = fmaxf(acc00 + int_b1[mj], 0.f);
    h1[bi * 256 + mj + 1]       = fmaxf(acc01 + int_b1[mj + 1], 0.f);
    h1[(bi + 1) * 256 + mj]     = fmaxf(acc10 + int_b1[mj], 0.f);
    h1[(bi + 1) * 256 + mj + 1] = fmaxf(acc11 + int_b1[mj + 1], 0.f);
}

// ---------------------------------------------------------------------------
// K4: tail MLP + output assembly.  one wave per batch row.
// ---------------------------------------------------------------------------
__global__ __launch_bounds__(64) void tail_kernel(
    const float* __restrict__ h1,
    const float* __restrict__ int_w2, const float* __restrict__ int_b2,
    const float* __restrict__ int_w3, const float* __restrict__ int_b3,
    const float* __restrict__ tw, const float* __restrict__ tb,
    const float* __restrict__ pw, const float* __restrict__ pb,
    const float* __restrict__ kw, const float* __restrict__ kb,
    const float* __restrict__ vw, const float* __restrict__ vb,
    const float* __restrict__ cw, const float* __restrict__ cb,
    const float* __restrict__ means,
    float* __restrict__ out)
{
    const int b = blockIdx.x;
    const int lane = threadIdx.x;
    __shared__ float h2s[64];
    __shared__ float ints[32];
    __shared__ float outs[16];

    {
        float acc = int_b2[lane];
        const float* hp = h1 + b * 256;
        const float* wp = int_w2 + lane * 256;
        for (int m = 0; m < 256; ++m) acc += wp[m] * hp[m];
        h2s[lane] = fmaxf(acc, 0.f);
    }
    __syncthreads();
    if (lane < 32) {
        float acc = int_b3[lane];
        const float* wp = int_w3 + lane * 64;
        for (int m = 0; m < 64; ++m) acc += wp[m] * h2s[m];
        ints[lane] = tanh2(acc);
    }
    __syncthreads();
    if (lane < 15) {
        const float* wsel; float bsel;
        if (lane < 3)       { wsel = tw + lane * 32;       bsel = tb[lane]; }
        else if (lane < 9)  { wsel = pw + (lane - 3) * 32; bsel = pb[lane - 3]; }
        else if (lane < 13) { wsel = kw + (lane - 9) * 32; bsel = kb[lane - 9]; }
        else if (lane == 13){ wsel = vw;                   bsel = vb[0]; }
        else                { wsel = cw;                   bsel = cb[0]; }
        float acc = bsel;
        for (int q = 0; q < 32; ++q) acc += wsel[q] * ints[q];
        outs[lane] = acc;
    }
    __syncthreads();
    if (lane < 20) {
        float v;
        if (lane < 15)       v = outs[lane];
        else if (lane == 15) v = sigf(outs[14]);
        else                 v = means[b * 4 + (lane - 16)];
        out[b * 20 + lane] = v;
    }
}

// ---------------------------------------------------------------------------
extern "C" void kernel_launch(void* const* d_in, const int* in_sizes, int n_in,
                              void* d_out, int out_size, void* d_ws, size_t ws_size,
                              hipStream_t stream)
{
    const float* x      = (const float*)d_in[0];
    const float* W_ih0  = (const float*)d_in[1];
    const float* W_hh0  = (const float*)d_in[2];
    const float* b_ih0  = (const float*)d_in[3];
    const float* b_hh0  = (const float*)d_in[4];
    const float* W_ih1  = (const float*)d_in[5];
    const float* W_hh1  = (const float*)d_in[6];
    const float* b_ih1  = (const float*)d_in[7];
    const float* b_hh1  = (const float*)d_in[8];
    const float* fp_w1  = (const float*)d_in[9];
    const float* fp_b1  = (const float*)d_in[10];
    const float* fp_w2  = (const float*)d_in[11];
    const float* fp_b2  = (const float*)d_in[12];
    const float* conn_w = (const float*)d_in[13];
    const float* sens   = (const float*)d_in[14];
    const float* thr    = (const float*)d_in[15];
    const float* int_w1 = (const float*)d_in[16];
    const float* int_b1 = (const float*)d_in[17];
    const float* int_w2 = (const float*)d_in[18];
    const float* int_b2 = (const float*)d_in[19];
    const float* int_w3 = (const float*)d_in[20];
    const float* int_b3 = (const float*)d_in[21];
    const float* tw     = (const float*)d_in[22];
    const float* tb     = (const float*)d_in[23];
    const float* pw     = (const float*)d_in[24];
    const float* pb     = (const float*)d_in[25];
    const float* kw     = (const float*)d_in[26];
    const float* kb     = (const float*)d_in[27];
    const float* vw     = (const float*)d_in[28];
    const float* vb     = (const float*)d_in[29];
    const float* cw     = (const float*)d_in[30];
    const float* cb     = (const float*)d_in[31];
    // d_in[32] = conn_idx -- unused: acts is a feat_sum broadcast, so the
    // gather/einsum collapses to feat_sum[b] * rowsum(conn_w)[n].

    float* ws = (float*)d_ws;
    float* out = (float*)d_out;

    prep_kernel<<<(PREP_TOTAL + 255) / 256, 256, 0, stream>>>(
        x, W_ih0, W_hh0, b_ih0, b_hh0, W_ih1, W_hh1, b_ih1, b_hh1,
        conn_w, sens, ws);

    lstm_mfma<<<NB / 16, 512, 0, stream>>>(
        ws, fp_w1, fp_b1, fp_w2, fp_b2, ws + OFF_FS);

    means_kernel<<<NB, 256, 0, stream>>>(
        ws + OFF_FS, ws + OFF_A, thr, ws + OFF_MEANS);

    {
        dim3 grid(NB / 32, 256 / 32);
        gemm_h1<<<grid, 256, 0, stream>>>(
            ws + OFF_FS, ws + OFF_A, thr, int_w1, int_b1, ws + OFF_H1);
    }

    tail_kernel<<<NB, 64, 0, stream>>>(
        ws + OFF_H1, int_w2, int_b2, int_w3, int_b3,
        tw, tb, pw, pb, kw, kb, vw, vb, cw, cb,
        ws + OFF_MEANS, out);
}